// Round 1
// baseline (1852.995 us; speedup 1.0000x reference)
//
#include <hip/hip_runtime.h>
#include <hip/hip_bf16.h>

// Phase 1: per-pair voltage contribution, scatter-add onto voltage[first].
// 4 pairs per thread via vector loads (coalesced 16B/lane on the streams).
__global__ void coulomb_pair_kernel(const float4* __restrict__ dist4,
                                    const int4*  __restrict__ first4,
                                    const int4*  __restrict__ second4,
                                    const float* __restrict__ charges,
                                    const float* __restrict__ ecf_p,
                                    float* __restrict__ voltage,
                                    int n4) {
    int i = blockIdx.x * blockDim.x + threadIdx.x;
    if (i >= n4) return;
    const float ecf = *ecf_p;

    int4   s = second4[i];
    float4 d = dist4[i];
    int4   f = first4[i];

    float v0 = ecf * charges[s.x] / d.x;
    float v1 = ecf * charges[s.y] / d.y;
    float v2 = ecf * charges[s.z] / d.z;
    float v3 = ecf * charges[s.w] / d.w;

    atomicAdd(&voltage[f.x], v0);
    atomicAdd(&voltage[f.y], v1);
    atomicAdd(&voltage[f.z], v2);
    atomicAdd(&voltage[f.w], v3);
}

// Tail (n_pairs not divisible by 4) — defensive; 32M is divisible by 4.
__global__ void coulomb_pair_tail(const float* __restrict__ dist,
                                  const int*  __restrict__ first,
                                  const int*  __restrict__ second,
                                  const float* __restrict__ charges,
                                  const float* __restrict__ ecf_p,
                                  float* __restrict__ voltage,
                                  int start, int n_pairs) {
    int p = start + blockIdx.x * blockDim.x + threadIdx.x;
    if (p >= n_pairs) return;
    float v = (*ecf_p) * charges[second[p]] / dist[p];
    atomicAdd(&voltage[first[p]], v);
}

// Phase 2: coulomb_atom = voltage*charge; 0.5*scatter-add onto molecules.
// 4 atoms per thread.
__global__ void coulomb_atom_kernel(const float4* __restrict__ charges4,
                                    const float4* __restrict__ voltage4,
                                    const int4*  __restrict__ mol4,
                                    float* __restrict__ mol_out,
                                    int n4) {
    int i = blockIdx.x * blockDim.x + threadIdx.x;
    if (i >= n4) return;
    float4 c = charges4[i];
    float4 v = voltage4[i];
    int4   m = mol4[i];
    atomicAdd(&mol_out[m.x], 0.5f * v.x * c.x);
    atomicAdd(&mol_out[m.y], 0.5f * v.y * c.y);
    atomicAdd(&mol_out[m.z], 0.5f * v.z * c.z);
    atomicAdd(&mol_out[m.w], 0.5f * v.w * c.w);
}

__global__ void coulomb_atom_tail(const float* __restrict__ charges,
                                  const float* __restrict__ voltage,
                                  const int*  __restrict__ mol_index,
                                  float* __restrict__ mol_out,
                                  int start, int n_atoms) {
    int a = start + blockIdx.x * blockDim.x + threadIdx.x;
    if (a >= n_atoms) return;
    atomicAdd(&mol_out[mol_index[a]], 0.5f * voltage[a] * charges[a]);
}

extern "C" void kernel_launch(void* const* d_in, const int* in_sizes, int n_in,
                              void* d_out, int out_size, void* d_ws, size_t ws_size,
                              hipStream_t stream) {
    const float* charges   = (const float*)d_in[0];
    const float* pair_dist = (const float*)d_in[1];
    const int*   pair_first  = (const int*)d_in[2];
    const int*   pair_second = (const int*)d_in[3];
    const int*   mol_index   = (const int*)d_in[4];
    // d_in[5] = n_molecules (int scalar) — derivable from sizes on host.
    const float* ecf_p = (const float*)d_in[6];

    const int n_atoms = in_sizes[0];
    const int n_pairs = in_sizes[1];
    const int n_mol   = out_size - n_atoms;

    float* mol_out = (float*)d_out;           // [n_mol]
    float* voltage = (float*)d_out + n_mol;   // [n_atoms]

    // Harness poisons d_out with 0xAA before every timed call — zero it.
    hipMemsetAsync(d_out, 0, (size_t)out_size * sizeof(float), stream);

    const int BLK = 256;

    // Phase 1
    {
        int n4 = n_pairs / 4;
        int grid = (n4 + BLK - 1) / BLK;
        if (grid > 0)
            coulomb_pair_kernel<<<grid, BLK, 0, stream>>>(
                (const float4*)pair_dist, (const int4*)pair_first,
                (const int4*)pair_second, charges, ecf_p, voltage, n4);
        int tail = n_pairs - n4 * 4;
        if (tail > 0)
            coulomb_pair_tail<<<1, BLK, 0, stream>>>(
                pair_dist, pair_first, pair_second, charges, ecf_p,
                voltage, n4 * 4, n_pairs);
    }

    // Phase 2 (ordered after phase 1 on the same stream)
    {
        int n4 = n_atoms / 4;
        int grid = (n4 + BLK - 1) / BLK;
        if (grid > 0)
            coulomb_atom_kernel<<<grid, BLK, 0, stream>>>(
                (const float4*)charges, (const float4*)voltage,
                (const int4*)mol_index, mol_out, n4);
        int tail = n_atoms - n4 * 4;
        if (tail > 0)
            coulomb_atom_tail<<<1, BLK, 0, stream>>>(
                charges, voltage, mol_index, mol_out, n4 * 4, n_atoms);
    }
}

// Round 2
// 1165.434 us; speedup vs baseline: 1.5900x; 1.5900x over previous
//
#include <hip/hip_runtime.h>
#include <hip/hip_bf16.h>

#define BUCKET_BITS 12
#define BUCKET_SIZE 4096           // atoms per bucket -> 16 KB LDS in reduce
#define PPB 16384                  // pairs per scatter block
#define BLK_A 256

// ---------------- fast path ----------------

__global__ void init_cursors(int* __restrict__ cur, int nbuckets, int cap) {
    int b = blockIdx.x * blockDim.x + threadIdx.x;
    if (b < nbuckets) cur[b] = b * cap;
}

// Two-pass per block: LDS histogram -> one global reservation atomic per
// bucket per block -> dense placement of (v, local_atom) entries.
__global__ __launch_bounds__(BLK_A) void pair_scatter(
    const int4*  __restrict__ first4,
    const int4*  __restrict__ second4,
    const float4* __restrict__ dist4,
    const float* __restrict__ charges,
    const float* __restrict__ ecf_p,
    int* __restrict__ cur,
    float2* __restrict__ entries,
    int n_pairs4) {
    __shared__ int hist[256];
    __shared__ int cursor[256];
    const int tid = threadIdx.x;
    hist[tid] = 0;
    __syncthreads();

    const int groups = PPB / 4;               // int4 groups per block
    const int base4 = blockIdx.x * groups;

    // pass 1: count (reads pair_first only)
    #pragma unroll 4
    for (int it = 0; it < groups / BLK_A; ++it) {
        int g = base4 + it * BLK_A + tid;
        if (g < n_pairs4) {
            int4 f = first4[g];
            atomicAdd(&hist[f.x >> BUCKET_BITS], 1);
            atomicAdd(&hist[f.y >> BUCKET_BITS], 1);
            atomicAdd(&hist[f.z >> BUCKET_BITS], 1);
            atomicAdd(&hist[f.w >> BUCKET_BITS], 1);
        }
    }
    __syncthreads();

    // reserve contiguous space in this bucket's region
    int cnt = hist[tid];
    if (cnt > 0) cursor[tid] = atomicAdd(&cur[tid], cnt);
    __syncthreads();

    const float ecf = *ecf_p;

    // pass 2: place
    #pragma unroll 2
    for (int it = 0; it < groups / BLK_A; ++it) {
        int g = base4 + it * BLK_A + tid;
        if (g < n_pairs4) {
            int4   f = first4[g];
            int4   s = second4[g];
            float4 d = dist4[g];
            float v0 = ecf * charges[s.x] / d.x;
            float v1 = ecf * charges[s.y] / d.y;
            float v2 = ecf * charges[s.z] / d.z;
            float v3 = ecf * charges[s.w] / d.w;
            int p0 = atomicAdd(&cursor[f.x >> BUCKET_BITS], 1);
            entries[p0] = make_float2(v0, __int_as_float(f.x & (BUCKET_SIZE - 1)));
            int p1 = atomicAdd(&cursor[f.y >> BUCKET_BITS], 1);
            entries[p1] = make_float2(v1, __int_as_float(f.y & (BUCKET_SIZE - 1)));
            int p2 = atomicAdd(&cursor[f.z >> BUCKET_BITS], 1);
            entries[p2] = make_float2(v2, __int_as_float(f.z & (BUCKET_SIZE - 1)));
            int p3 = atomicAdd(&cursor[f.w >> BUCKET_BITS], 1);
            entries[p3] = make_float2(v3, __int_as_float(f.w & (BUCKET_SIZE - 1)));
        }
    }
}

// One block per bucket: LDS-privatized voltage tile, exclusive writeback.
__global__ __launch_bounds__(1024) void bucket_reduce(
    const float2* __restrict__ entries,
    const int* __restrict__ cur,
    float* __restrict__ voltage,
    int cap, int n_atoms) {
    __shared__ float volt[BUCKET_SIZE];
    const int b = blockIdx.x;
    for (int i = threadIdx.x; i < BUCKET_SIZE; i += blockDim.x) volt[i] = 0.f;
    __syncthreads();
    const int start = b * cap;
    const int end = cur[b];                   // final cursor == start + count
    for (int i = start + threadIdx.x; i < end; i += blockDim.x) {
        float2 e = entries[i];
        atomicAdd(&volt[__float_as_int(e.y)], e.x);
    }
    __syncthreads();
    const int abase = b << BUCKET_BITS;
    const int nat = min(BUCKET_SIZE, n_atoms - abase);
    for (int i = threadIdx.x; i < nat; i += blockDim.x)
        voltage[abase + i] = volt[i];
}

// LDS-privatized molecule reduction.
__global__ __launch_bounds__(1024) void mol_reduce(
    const float* __restrict__ charges,
    const float* __restrict__ voltage,
    const int*  __restrict__ mol_index,
    float* __restrict__ mol_out,
    int n_mol, int n_atoms) {
    extern __shared__ float smem[];
    for (int i = threadIdx.x; i < n_mol; i += blockDim.x) smem[i] = 0.f;
    __syncthreads();
    const int n4 = n_atoms >> 2;
    const int gid = blockIdx.x * blockDim.x + threadIdx.x;
    const int stride = gridDim.x * blockDim.x;
    const float4* c4p = (const float4*)charges;
    const float4* v4p = (const float4*)voltage;
    const int4*   m4p = (const int4*)mol_index;
    for (int i = gid; i < n4; i += stride) {
        float4 c = c4p[i]; float4 v = v4p[i]; int4 m = m4p[i];
        atomicAdd(&smem[m.x], 0.5f * v.x * c.x);
        atomicAdd(&smem[m.y], 0.5f * v.y * c.y);
        atomicAdd(&smem[m.z], 0.5f * v.z * c.z);
        atomicAdd(&smem[m.w], 0.5f * v.w * c.w);
    }
    for (int i = (n4 << 2) + gid; i < n_atoms; i += stride)
        atomicAdd(&smem[mol_index[i]], 0.5f * voltage[i] * charges[i]);
    __syncthreads();
    for (int i = threadIdx.x; i < n_mol; i += blockDim.x)
        atomicAdd(&mol_out[i], smem[i]);
}

// ---------------- fallback path (direct atomics, known-correct) ----------------

__global__ void coulomb_pair_direct(const float* __restrict__ dist,
                                    const int*  __restrict__ first,
                                    const int*  __restrict__ second,
                                    const float* __restrict__ charges,
                                    const float* __restrict__ ecf_p,
                                    float* __restrict__ voltage,
                                    int n_pairs) {
    int p = blockIdx.x * blockDim.x + threadIdx.x;
    if (p >= n_pairs) return;
    float v = (*ecf_p) * charges[second[p]] / dist[p];
    atomicAdd(&voltage[first[p]], v);
}

__global__ void coulomb_atom_direct(const float* __restrict__ charges,
                                    const float* __restrict__ voltage,
                                    const int*  __restrict__ mol_index,
                                    float* __restrict__ mol_out,
                                    int n_atoms) {
    int a = blockIdx.x * blockDim.x + threadIdx.x;
    if (a >= n_atoms) return;
    atomicAdd(&mol_out[mol_index[a]], 0.5f * voltage[a] * charges[a]);
}

extern "C" void kernel_launch(void* const* d_in, const int* in_sizes, int n_in,
                              void* d_out, int out_size, void* d_ws, size_t ws_size,
                              hipStream_t stream) {
    const float* charges     = (const float*)d_in[0];
    const float* pair_dist   = (const float*)d_in[1];
    const int*   pair_first  = (const int*)d_in[2];
    const int*   pair_second = (const int*)d_in[3];
    const int*   mol_index   = (const int*)d_in[4];
    const float* ecf_p       = (const float*)d_in[6];

    const int n_atoms = in_sizes[0];
    const int n_pairs = in_sizes[1];
    const int n_mol   = out_size - n_atoms;

    float* mol_out = (float*)d_out;           // [n_mol]
    float* voltage = (float*)d_out + n_mol;   // [n_atoms]

    const int nbuckets = (n_atoms + BUCKET_SIZE - 1) >> BUCKET_BITS;
    long long capll = (long long)n_pairs / (nbuckets > 0 ? nbuckets : 1);
    capll += capll / 16 + 4096;               // >25 sigma headroom for uniform keys
    long long tot_entries = capll * nbuckets;
    size_t entries_bytes = (size_t)tot_entries * sizeof(float2);
    size_t cur_off = (entries_bytes + 255) & ~(size_t)255;
    size_t need = cur_off + (size_t)nbuckets * sizeof(int);

    const bool mol_lds_ok = (size_t)n_mol * sizeof(float) <= 60 * 1024;
    const bool fast = (nbuckets >= 1) && (nbuckets <= 256) &&
                      (tot_entries < 0x7fffffffLL) &&
                      ((n_pairs & 3) == 0) &&
                      (need <= ws_size);

    if (fast) {
        // zero molecule accumulators only; voltage region is fully overwritten
        hipMemsetAsync(d_out, 0, (size_t)n_mol * sizeof(float), stream);

        float2* entries = (float2*)d_ws;
        int* cur = (int*)((char*)d_ws + cur_off);
        const int cap = (int)capll;

        init_cursors<<<1, 256, 0, stream>>>(cur, nbuckets, cap);

        const int n_pairs4 = n_pairs >> 2;
        const int nblocks = (n_pairs + PPB - 1) / PPB;
        pair_scatter<<<nblocks, BLK_A, 0, stream>>>(
            (const int4*)pair_first, (const int4*)pair_second,
            (const float4*)pair_dist, charges, ecf_p, cur, entries, n_pairs4);

        bucket_reduce<<<nbuckets, 1024, 0, stream>>>(entries, cur, voltage,
                                                     cap, n_atoms);

        if (mol_lds_ok) {
            mol_reduce<<<64, 1024, n_mol * sizeof(float), stream>>>(
                charges, voltage, mol_index, mol_out, n_mol, n_atoms);
        } else {
            coulomb_atom_direct<<<(n_atoms + 255) / 256, 256, 0, stream>>>(
                charges, voltage, mol_index, mol_out, n_atoms);
        }
    } else {
        // fallback: direct global atomics (round-1 behavior)
        hipMemsetAsync(d_out, 0, (size_t)out_size * sizeof(float), stream);
        coulomb_pair_direct<<<(n_pairs + 255) / 256, 256, 0, stream>>>(
            pair_dist, pair_first, pair_second, charges, ecf_p, voltage, n_pairs);
        coulomb_atom_direct<<<(n_atoms + 255) / 256, 256, 0, stream>>>(
            charges, voltage, mol_index, mol_out, n_atoms);
    }
}

// Round 3
// 820.204 us; speedup vs baseline: 2.2592x; 1.4209x over previous
//
#include <hip/hip_runtime.h>
#include <hip/hip_fp16.h>

#define BUCKET_BITS 12
#define BUCKET_SIZE 4096           // atoms per bucket -> 16 KB LDS tile in reduce
#define NB 256                     // max buckets (n_atoms <= 1M)
#define PPB 16384                  // pairs per scatter block (64 KB LDS staging)
#define BLK_A 256

// ---------------- fast path ----------------

__global__ void init_cursors(int* __restrict__ cur, int nbuckets, int cap) {
    int b = blockIdx.x * blockDim.x + threadIdx.x;
    if (b < nbuckets) cur[b] = b * cap;
}

// Block-level counting sort: histogram -> prefix scan -> place into LDS
// sorted by bucket -> cooperative coalesced flush to per-bucket global
// regions (one reservation atomic per bucket per block).
// Entry = (local_atom_idx << 16) | fp16_bits(v)  -- 4 bytes.
__global__ __launch_bounds__(BLK_A) void pair_scatter(
    const int4*   __restrict__ first4,
    const int4*   __restrict__ second4,
    const float4* __restrict__ dist4,
    const float*  __restrict__ charges,
    const float*  __restrict__ ecf_p,
    int* __restrict__ cur,
    unsigned* __restrict__ entries,
    int n_pairs4) {
    __shared__ unsigned stag[PPB];
    __shared__ int hist[NB];
    __shared__ int scanA[NB];
    __shared__ int lofs[NB + 1];
    __shared__ int gadj[NB];

    const int tid = threadIdx.x;
    hist[tid] = 0;
    __syncthreads();

    const int groups = PPB / 4;               // int4 groups per block
    const int base4 = blockIdx.x * groups;

    // pass 1: histogram (reads pair_first only)
    #pragma unroll 4
    for (int it = 0; it < groups / BLK_A; ++it) {
        int g = base4 + it * BLK_A + tid;
        if (g < n_pairs4) {
            int4 f = first4[g];
            atomicAdd(&hist[f.x >> BUCKET_BITS], 1);
            atomicAdd(&hist[f.y >> BUCKET_BITS], 1);
            atomicAdd(&hist[f.z >> BUCKET_BITS], 1);
            atomicAdd(&hist[f.w >> BUCKET_BITS], 1);
        }
    }
    __syncthreads();

    // exclusive prefix scan over 256 buckets (Hillis-Steele in LDS)
    scanA[tid] = hist[tid];
    __syncthreads();
    for (int off = 1; off < NB; off <<= 1) {
        int v = scanA[tid];
        if (tid >= off) v += scanA[tid - off];
        __syncthreads();
        scanA[tid] = v;
        __syncthreads();
    }
    if (tid == 0) lofs[0] = 0;
    lofs[tid + 1] = scanA[tid];
    __syncthreads();

    // reserve this block's contiguous range in each bucket's global region
    int cnt = hist[tid];
    if (cnt > 0) gadj[tid] = atomicAdd(&cur[tid], cnt) - lofs[tid];
    hist[tid] = lofs[tid];   // reuse hist as the local placement cursor
    __syncthreads();

    const float ecf = *ecf_p;

    // pass 2: compute v, place sorted-by-bucket into LDS staging
    #pragma unroll 2
    for (int it = 0; it < groups / BLK_A; ++it) {
        int g = base4 + it * BLK_A + tid;
        if (g < n_pairs4) {
            int4   f = first4[g];
            int4   s = second4[g];
            float4 d = dist4[g];
            float v0 = ecf * charges[s.x] / d.x;
            float v1 = ecf * charges[s.y] / d.y;
            float v2 = ecf * charges[s.z] / d.z;
            float v3 = ecf * charges[s.w] / d.w;
            int p0 = atomicAdd(&hist[f.x >> BUCKET_BITS], 1);
            stag[p0] = ((unsigned)(f.x & (BUCKET_SIZE - 1)) << 16) |
                       (unsigned)__half_as_ushort(__float2half(v0));
            int p1 = atomicAdd(&hist[f.y >> BUCKET_BITS], 1);
            stag[p1] = ((unsigned)(f.y & (BUCKET_SIZE - 1)) << 16) |
                       (unsigned)__half_as_ushort(__float2half(v1));
            int p2 = atomicAdd(&hist[f.z >> BUCKET_BITS], 1);
            stag[p2] = ((unsigned)(f.z & (BUCKET_SIZE - 1)) << 16) |
                       (unsigned)__half_as_ushort(__float2half(v2));
            int p3 = atomicAdd(&hist[f.w >> BUCKET_BITS], 1);
            stag[p3] = ((unsigned)(f.w & (BUCKET_SIZE - 1)) << 16) |
                       (unsigned)__half_as_ushort(__float2half(v3));
        }
    }
    __syncthreads();

    // coalesced flush: flat index i -> bucket via binary search in lofs;
    // consecutive i within a bucket run -> consecutive global addresses.
    const int tot = lofs[NB];
    for (int i = tid; i < tot; i += BLK_A) {
        unsigned e = stag[i];
        int lo = 0, hi = NB - 1;
        #pragma unroll
        for (int s = 0; s < 8; ++s) {
            int mid = (lo + hi + 1) >> 1;
            if (lofs[mid] <= i) lo = mid; else hi = mid - 1;
        }
        entries[gadj[lo] + i] = e;
    }
}

// One block per bucket: LDS-privatized voltage tile, exclusive writeback.
__global__ __launch_bounds__(1024) void bucket_reduce(
    const unsigned* __restrict__ entries,
    const int* __restrict__ cur,
    float* __restrict__ voltage,
    int cap, int n_atoms) {
    __shared__ float volt[BUCKET_SIZE];
    const int b = blockIdx.x;
    for (int i = threadIdx.x; i < BUCKET_SIZE; i += blockDim.x) volt[i] = 0.f;
    __syncthreads();
    const int start = b * cap;
    const int end = cur[b];                   // final cursor == start + count
    for (int i = start + threadIdx.x; i < end; i += blockDim.x) {
        unsigned e = entries[i];
        float v = __half2float(__ushort_as_half((unsigned short)(e & 0xFFFFu)));
        atomicAdd(&volt[e >> 16], v);
    }
    __syncthreads();
    const int abase = b << BUCKET_BITS;
    const int nat = min(BUCKET_SIZE, n_atoms - abase);
    for (int i = threadIdx.x; i < nat; i += blockDim.x)
        voltage[abase + i] = volt[i];
}

// LDS-privatized molecule reduction.
__global__ __launch_bounds__(1024) void mol_reduce(
    const float* __restrict__ charges,
    const float* __restrict__ voltage,
    const int*  __restrict__ mol_index,
    float* __restrict__ mol_out,
    int n_mol, int n_atoms) {
    extern __shared__ float smem[];
    for (int i = threadIdx.x; i < n_mol; i += blockDim.x) smem[i] = 0.f;
    __syncthreads();
    const int n4 = n_atoms >> 2;
    const int gid = blockIdx.x * blockDim.x + threadIdx.x;
    const int stride = gridDim.x * blockDim.x;
    const float4* c4p = (const float4*)charges;
    const float4* v4p = (const float4*)voltage;
    const int4*   m4p = (const int4*)mol_index;
    for (int i = gid; i < n4; i += stride) {
        float4 c = c4p[i]; float4 v = v4p[i]; int4 m = m4p[i];
        atomicAdd(&smem[m.x], 0.5f * v.x * c.x);
        atomicAdd(&smem[m.y], 0.5f * v.y * c.y);
        atomicAdd(&smem[m.z], 0.5f * v.z * c.z);
        atomicAdd(&smem[m.w], 0.5f * v.w * c.w);
    }
    for (int i = (n4 << 2) + gid; i < n_atoms; i += stride)
        atomicAdd(&smem[mol_index[i]], 0.5f * voltage[i] * charges[i]);
    __syncthreads();
    for (int i = threadIdx.x; i < n_mol; i += blockDim.x)
        atomicAdd(&mol_out[i], smem[i]);
}

// ---------------- fallback path (direct atomics, known-correct) ----------------

__global__ void coulomb_pair_direct(const float* __restrict__ dist,
                                    const int*  __restrict__ first,
                                    const int*  __restrict__ second,
                                    const float* __restrict__ charges,
                                    const float* __restrict__ ecf_p,
                                    float* __restrict__ voltage,
                                    int n_pairs) {
    int p = blockIdx.x * blockDim.x + threadIdx.x;
    if (p >= n_pairs) return;
    float v = (*ecf_p) * charges[second[p]] / dist[p];
    atomicAdd(&voltage[first[p]], v);
}

__global__ void coulomb_atom_direct(const float* __restrict__ charges,
                                    const float* __restrict__ voltage,
                                    const int*  __restrict__ mol_index,
                                    float* __restrict__ mol_out,
                                    int n_atoms) {
    int a = blockIdx.x * blockDim.x + threadIdx.x;
    if (a >= n_atoms) return;
    atomicAdd(&mol_out[mol_index[a]], 0.5f * voltage[a] * charges[a]);
}

extern "C" void kernel_launch(void* const* d_in, const int* in_sizes, int n_in,
                              void* d_out, int out_size, void* d_ws, size_t ws_size,
                              hipStream_t stream) {
    const float* charges     = (const float*)d_in[0];
    const float* pair_dist   = (const float*)d_in[1];
    const int*   pair_first  = (const int*)d_in[2];
    const int*   pair_second = (const int*)d_in[3];
    const int*   mol_index   = (const int*)d_in[4];
    const float* ecf_p       = (const float*)d_in[6];

    const int n_atoms = in_sizes[0];
    const int n_pairs = in_sizes[1];
    const int n_mol   = out_size - n_atoms;

    float* mol_out = (float*)d_out;           // [n_mol]
    float* voltage = (float*)d_out + n_mol;   // [n_atoms]

    const int nbuckets = (n_atoms + BUCKET_SIZE - 1) >> BUCKET_BITS;
    long long capll = (long long)n_pairs / (nbuckets > 0 ? nbuckets : 1);
    capll += capll / 16 + 4096;               // >20 sigma headroom for uniform keys
    capll = (capll + 3) & ~3LL;               // 16B-align bucket bases
    long long tot_entries = capll * nbuckets;
    size_t entries_bytes = (size_t)tot_entries * sizeof(unsigned);
    size_t cur_off = (entries_bytes + 255) & ~(size_t)255;
    size_t need = cur_off + (size_t)nbuckets * sizeof(int);

    const bool mol_lds_ok = (size_t)n_mol * sizeof(float) <= 60 * 1024;
    const bool fast = (nbuckets >= 1) && (nbuckets <= NB) &&
                      (tot_entries < 0x7fffffffLL) &&
                      ((n_pairs & 3) == 0) &&
                      (need <= ws_size);

    if (fast) {
        // zero molecule accumulators only; voltage region is fully overwritten
        hipMemsetAsync(d_out, 0, (size_t)n_mol * sizeof(float), stream);

        unsigned* entries = (unsigned*)d_ws;
        int* cur = (int*)((char*)d_ws + cur_off);
        const int cap = (int)capll;

        init_cursors<<<1, 256, 0, stream>>>(cur, nbuckets, cap);

        const int n_pairs4 = n_pairs >> 2;
        const int nblocks = (n_pairs + PPB - 1) / PPB;
        pair_scatter<<<nblocks, BLK_A, 0, stream>>>(
            (const int4*)pair_first, (const int4*)pair_second,
            (const float4*)pair_dist, charges, ecf_p, cur, entries, n_pairs4);

        bucket_reduce<<<nbuckets, 1024, 0, stream>>>(entries, cur, voltage,
                                                     cap, n_atoms);

        if (mol_lds_ok) {
            mol_reduce<<<64, 1024, n_mol * sizeof(float), stream>>>(
                charges, voltage, mol_index, mol_out, n_mol, n_atoms);
        } else {
            coulomb_atom_direct<<<(n_atoms + 255) / 256, 256, 0, stream>>>(
                charges, voltage, mol_index, mol_out, n_atoms);
        }
    } else {
        // fallback: direct global atomics (round-1 behavior)
        hipMemsetAsync(d_out, 0, (size_t)out_size * sizeof(float), stream);
        coulomb_pair_direct<<<(n_pairs + 255) / 256, 256, 0, stream>>>(
            pair_dist, pair_first, pair_second, charges, ecf_p, voltage, n_pairs);
        coulomb_atom_direct<<<(n_atoms + 255) / 256, 256, 0, stream>>>(
            charges, voltage, mol_index, mol_out, n_atoms);
    }
}

// Round 4
// 807.408 us; speedup vs baseline: 2.2950x; 1.0158x over previous
//
#include <hip/hip_runtime.h>
#include <hip/hip_fp16.h>

#define BUCKET_BITS 12
#define BUCKET_SIZE 4096           // atoms per bucket -> 16 KB LDS tile in reduce
#define NB 256                     // max buckets (n_atoms <= 1M)
#define PPB 8192                   // pairs per scatter block (32 KB LDS staging)
#define BLK_A 256
#define MOL_BLOCKS 64

// ---------------- fast path ----------------

__global__ void init_cursors(int* __restrict__ cur, int nbuckets, int cap) {
    int b = blockIdx.x * blockDim.x + threadIdx.x;
    if (b < nbuckets) cur[b] = b * cap;
}

// Block-level counting sort: histogram -> prefix scan -> place into LDS
// sorted by bucket -> cooperative coalesced flush to per-bucket global
// regions (one reservation atomic per bucket per block).
// Entry = (local_atom_idx << 16) | fp16_bits(v)  -- 4 bytes.
// LDS ~37 KB -> 4 blocks/CU (vs 70 KB/2 blocks in R3).
__global__ __launch_bounds__(BLK_A) void pair_scatter(
    const int4*   __restrict__ first4,
    const int4*   __restrict__ second4,
    const float4* __restrict__ dist4,
    const float*  __restrict__ charges,
    const float*  __restrict__ ecf_p,
    int* __restrict__ cur,
    unsigned* __restrict__ entries,
    int n_pairs4) {
    __shared__ unsigned stag[PPB];
    __shared__ int hist[NB];
    __shared__ int scanA[NB];
    __shared__ int lofs[NB + 1];
    __shared__ int gadj[NB];

    const int tid = threadIdx.x;
    hist[tid] = 0;
    __syncthreads();

    const int groups = PPB / 4;               // int4 groups per block
    const int base4 = blockIdx.x * groups;

    // pass 1: histogram (reads pair_first only)
    #pragma unroll
    for (int it = 0; it < groups / BLK_A; ++it) {
        int g = base4 + it * BLK_A + tid;
        if (g < n_pairs4) {
            int4 f = first4[g];
            atomicAdd(&hist[f.x >> BUCKET_BITS], 1);
            atomicAdd(&hist[f.y >> BUCKET_BITS], 1);
            atomicAdd(&hist[f.z >> BUCKET_BITS], 1);
            atomicAdd(&hist[f.w >> BUCKET_BITS], 1);
        }
    }
    __syncthreads();

    // exclusive prefix scan over 256 buckets (Hillis-Steele in LDS)
    scanA[tid] = hist[tid];
    __syncthreads();
    for (int off = 1; off < NB; off <<= 1) {
        int v = scanA[tid];
        if (tid >= off) v += scanA[tid - off];
        __syncthreads();
        scanA[tid] = v;
        __syncthreads();
    }
    if (tid == 0) lofs[0] = 0;
    lofs[tid + 1] = scanA[tid];
    __syncthreads();

    // reserve this block's contiguous range in each bucket's global region
    int cnt = hist[tid];
    if (cnt > 0) gadj[tid] = atomicAdd(&cur[tid], cnt) - lofs[tid];
    hist[tid] = lofs[tid];   // reuse hist as the local placement cursor
    __syncthreads();

    const float ecf = *ecf_p;

    // pass 2: compute v, place sorted-by-bucket into LDS staging
    #pragma unroll
    for (int it = 0; it < groups / BLK_A; ++it) {
        int g = base4 + it * BLK_A + tid;
        if (g < n_pairs4) {
            int4   f = first4[g];
            int4   s = second4[g];
            float4 d = dist4[g];
            float v0 = ecf * charges[s.x] / d.x;
            float v1 = ecf * charges[s.y] / d.y;
            float v2 = ecf * charges[s.z] / d.z;
            float v3 = ecf * charges[s.w] / d.w;
            int p0 = atomicAdd(&hist[f.x >> BUCKET_BITS], 1);
            stag[p0] = ((unsigned)(f.x & (BUCKET_SIZE - 1)) << 16) |
                       (unsigned)__half_as_ushort(__float2half(v0));
            int p1 = atomicAdd(&hist[f.y >> BUCKET_BITS], 1);
            stag[p1] = ((unsigned)(f.y & (BUCKET_SIZE - 1)) << 16) |
                       (unsigned)__half_as_ushort(__float2half(v1));
            int p2 = atomicAdd(&hist[f.z >> BUCKET_BITS], 1);
            stag[p2] = ((unsigned)(f.z & (BUCKET_SIZE - 1)) << 16) |
                       (unsigned)__half_as_ushort(__float2half(v2));
            int p3 = atomicAdd(&hist[f.w >> BUCKET_BITS], 1);
            stag[p3] = ((unsigned)(f.w & (BUCKET_SIZE - 1)) << 16) |
                       (unsigned)__half_as_ushort(__float2half(v3));
        }
    }
    __syncthreads();

    // coalesced flush: flat index i -> bucket via binary search in lofs;
    // consecutive i within a bucket run -> consecutive global addresses.
    const int tot = lofs[NB];
    for (int i = tid; i < tot; i += BLK_A) {
        unsigned e = stag[i];
        int lo = 0, hi = NB - 1;
        #pragma unroll
        for (int s = 0; s < 8; ++s) {
            int mid = (lo + hi + 1) >> 1;
            if (lofs[mid] <= i) lo = mid; else hi = mid - 1;
        }
        entries[gadj[lo] + i] = e;
    }
}

// One block per bucket: LDS-privatized voltage tile, exclusive writeback.
// Entries read as uint4 (16 B/lane).
__global__ __launch_bounds__(1024) void bucket_reduce(
    const unsigned* __restrict__ entries,
    const int* __restrict__ cur,
    float* __restrict__ voltage,
    int cap, int n_atoms) {
    __shared__ float volt[BUCKET_SIZE];
    const int b = blockIdx.x;
    for (int i = threadIdx.x; i < BUCKET_SIZE; i += blockDim.x) volt[i] = 0.f;
    __syncthreads();
    const int start = b * cap;                // cap multiple of 4 -> 16B aligned
    const int end = cur[b];                   // final cursor == start + count
    const int cnt = end - start;
    const int cnt4 = cnt >> 2;
    const uint4* e4p = (const uint4*)(entries + start);
    for (int i = threadIdx.x; i < cnt4; i += blockDim.x) {
        uint4 e = e4p[i];
        atomicAdd(&volt[e.x >> 16], __half2float(__ushort_as_half((unsigned short)(e.x & 0xFFFFu))));
        atomicAdd(&volt[e.y >> 16], __half2float(__ushort_as_half((unsigned short)(e.y & 0xFFFFu))));
        atomicAdd(&volt[e.z >> 16], __half2float(__ushort_as_half((unsigned short)(e.z & 0xFFFFu))));
        atomicAdd(&volt[e.w >> 16], __half2float(__ushort_as_half((unsigned short)(e.w & 0xFFFFu))));
    }
    for (int i = (cnt4 << 2) + threadIdx.x; i < cnt; i += blockDim.x) {
        unsigned e = entries[start + i];
        atomicAdd(&volt[e >> 16], __half2float(__ushort_as_half((unsigned short)(e & 0xFFFFu))));
    }
    __syncthreads();
    const int abase = b << BUCKET_BITS;
    const int nat = min(BUCKET_SIZE, n_atoms - abase);
    for (int i = threadIdx.x; i < nat; i += blockDim.x)
        voltage[abase + i] = volt[i];
}

// Hierarchical molecule reduction: per-block LDS partials -> dense ws store.
__global__ __launch_bounds__(1024) void mol_partial(
    const float* __restrict__ charges,
    const float* __restrict__ voltage,
    const int*  __restrict__ mol_index,
    float* __restrict__ partials,
    int n_mol, int n_atoms) {
    extern __shared__ float smem[];
    for (int i = threadIdx.x; i < n_mol; i += blockDim.x) smem[i] = 0.f;
    __syncthreads();
    const int n4 = n_atoms >> 2;
    const int gid = blockIdx.x * blockDim.x + threadIdx.x;
    const int stride = gridDim.x * blockDim.x;
    const float4* c4p = (const float4*)charges;
    const float4* v4p = (const float4*)voltage;
    const int4*   m4p = (const int4*)mol_index;
    for (int i = gid; i < n4; i += stride) {
        float4 c = c4p[i]; float4 v = v4p[i]; int4 m = m4p[i];
        atomicAdd(&smem[m.x], 0.5f * v.x * c.x);
        atomicAdd(&smem[m.y], 0.5f * v.y * c.y);
        atomicAdd(&smem[m.z], 0.5f * v.z * c.z);
        atomicAdd(&smem[m.w], 0.5f * v.w * c.w);
    }
    for (int i = (n4 << 2) + gid; i < n_atoms; i += stride)
        atomicAdd(&smem[mol_index[i]], 0.5f * voltage[i] * charges[i]);
    __syncthreads();
    float* dst = partials + (size_t)blockIdx.x * n_mol;
    for (int i = threadIdx.x; i < n_mol; i += blockDim.x)
        dst[i] = smem[i];
}

__global__ void mol_final(const float* __restrict__ partials,
                          float* __restrict__ mol_out,
                          int n_mol, int nparts) {
    int m = blockIdx.x * blockDim.x + threadIdx.x;
    if (m >= n_mol) return;
    float s = 0.f;
    for (int p = 0; p < nparts; ++p) s += partials[(size_t)p * n_mol + m];
    mol_out[m] = s;
}

// ---------------- fallback path (direct atomics, known-correct) ----------------

__global__ void coulomb_pair_direct(const float* __restrict__ dist,
                                    const int*  __restrict__ first,
                                    const int*  __restrict__ second,
                                    const float* __restrict__ charges,
                                    const float* __restrict__ ecf_p,
                                    float* __restrict__ voltage,
                                    int n_pairs) {
    int p = blockIdx.x * blockDim.x + threadIdx.x;
    if (p >= n_pairs) return;
    float v = (*ecf_p) * charges[second[p]] / dist[p];
    atomicAdd(&voltage[first[p]], v);
}

__global__ void coulomb_atom_direct(const float* __restrict__ charges,
                                    const float* __restrict__ voltage,
                                    const int*  __restrict__ mol_index,
                                    float* __restrict__ mol_out,
                                    int n_atoms) {
    int a = blockIdx.x * blockDim.x + threadIdx.x;
    if (a >= n_atoms) return;
    atomicAdd(&mol_out[mol_index[a]], 0.5f * voltage[a] * charges[a]);
}

extern "C" void kernel_launch(void* const* d_in, const int* in_sizes, int n_in,
                              void* d_out, int out_size, void* d_ws, size_t ws_size,
                              hipStream_t stream) {
    const float* charges     = (const float*)d_in[0];
    const float* pair_dist   = (const float*)d_in[1];
    const int*   pair_first  = (const int*)d_in[2];
    const int*   pair_second = (const int*)d_in[3];
    const int*   mol_index   = (const int*)d_in[4];
    const float* ecf_p       = (const float*)d_in[6];

    const int n_atoms = in_sizes[0];
    const int n_pairs = in_sizes[1];
    const int n_mol   = out_size - n_atoms;

    float* mol_out = (float*)d_out;           // [n_mol]
    float* voltage = (float*)d_out + n_mol;   // [n_atoms]

    const int nbuckets = (n_atoms + BUCKET_SIZE - 1) >> BUCKET_BITS;
    long long capll = (long long)n_pairs / (nbuckets > 0 ? nbuckets : 1);
    capll += capll / 16 + 4096;               // >20 sigma headroom for uniform keys
    capll = (capll + 3) & ~3LL;               // 16B-align bucket bases
    long long tot_entries = capll * nbuckets;
    size_t entries_bytes = (size_t)tot_entries * sizeof(unsigned);
    size_t cur_off = (entries_bytes + 255) & ~(size_t)255;
    size_t mol_off = (cur_off + (size_t)nbuckets * sizeof(int) + 255) & ~(size_t)255;
    size_t need_base = cur_off + (size_t)nbuckets * sizeof(int);
    size_t need_mol  = mol_off + (size_t)MOL_BLOCKS * n_mol * sizeof(float);

    const bool mol_lds_ok = (size_t)n_mol * sizeof(float) <= 60 * 1024;
    const bool fast = (nbuckets >= 1) && (nbuckets <= NB) &&
                      (tot_entries < 0x7fffffffLL) &&
                      ((n_pairs & 3) == 0) &&
                      (need_base <= ws_size);
    const bool mol_hier = fast && mol_lds_ok && (need_mol <= ws_size);

    if (fast) {
        unsigned* entries = (unsigned*)d_ws;
        int* cur = (int*)((char*)d_ws + cur_off);
        const int cap = (int)capll;

        init_cursors<<<1, 256, 0, stream>>>(cur, nbuckets, cap);

        const int n_pairs4 = n_pairs >> 2;
        const int nblocks = (n_pairs + PPB - 1) / PPB;
        pair_scatter<<<nblocks, BLK_A, 0, stream>>>(
            (const int4*)pair_first, (const int4*)pair_second,
            (const float4*)pair_dist, charges, ecf_p, cur, entries, n_pairs4);

        bucket_reduce<<<nbuckets, 1024, 0, stream>>>(entries, cur, voltage,
                                                     cap, n_atoms);

        if (mol_hier) {
            float* partials = (float*)((char*)d_ws + mol_off);
            mol_partial<<<MOL_BLOCKS, 1024, n_mol * sizeof(float), stream>>>(
                charges, voltage, mol_index, partials, n_mol, n_atoms);
            mol_final<<<(n_mol + 255) / 256, 256, 0, stream>>>(
                partials, mol_out, n_mol, MOL_BLOCKS);
        } else {
            hipMemsetAsync(d_out, 0, (size_t)n_mol * sizeof(float), stream);
            coulomb_atom_direct<<<(n_atoms + 255) / 256, 256, 0, stream>>>(
                charges, voltage, mol_index, mol_out, n_atoms);
        }
    } else {
        // fallback: direct global atomics (round-1 behavior)
        hipMemsetAsync(d_out, 0, (size_t)out_size * sizeof(float), stream);
        coulomb_pair_direct<<<(n_pairs + 255) / 256, 256, 0, stream>>>(
            pair_dist, pair_first, pair_second, charges, ecf_p, voltage, n_pairs);
        coulomb_atom_direct<<<(n_atoms + 255) / 256, 256, 0, stream>>>(
            charges, voltage, mol_index, mol_out, n_atoms);
    }
}